// Round 1
// baseline (228.716 us; speedup 1.0000x reference)
//
#include <hip/hip_runtime.h>
#include <cstdint>

#define N_ 4
#define L_ 8192
#define S_ 8192
#define H_ 8
#define D_ 64
#define E_ 64
#define EPS_ 1e-6f

__device__ __forceinline__ float elu1(float x) {
  // elu(x)+1 : x>0 ? x+1 : exp(x)
  return x > 0.0f ? x + 1.0f : __expf(x);
}

// ---------------- zero init for KV/Ksum accumulators ----------------
__global__ void zero_ws_kernel(float4* p, int n4) {
  int i = blockIdx.x * blockDim.x + threadIdx.x;
  if (i < n4) p[i] = make_float4(0.f, 0.f, 0.f, 0.f);
}

// ---------------- phase 1: KV[d][e] = sum_s fK[s][d] * Vraw[s][e]; Ksum[d] ----------------
// grid (32, H, N), block 256 (4 waves). Each wave covers 64 s-rows.
__global__ __launch_bounds__(256) void p1_kv(const float* __restrict__ keys,
                                             const float* __restrict__ values,
                                             float* __restrict__ kvg,
                                             float* __restrict__ ksg) {
  const int chunk = blockIdx.x, h = blockIdx.y, n = blockIdx.z;
  const int wave = threadIdx.x >> 6, lane = threadIdx.x & 63;
  __shared__ float smem[64 * 64];   // staging [4 waves][4 rows][64] (4KiB), reused as [64][64] reduce
  __shared__ float ksm[64];

  const size_t bhead = (size_t)n * S_ * (H_ * D_) + (size_t)h * D_ + lane;
  const float* Kb = keys + bhead;
  const float* Vb = values + bhead;
  const int s0 = chunk * 256 + wave * 64;

  float acc[64];
  #pragma unroll
  for (int d = 0; d < 64; d++) acc[d] = 0.0f;
  float ksacc = 0.0f;

  float* stg = &smem[wave * 4 * 64];
  float krA[4], vvA[4], krB[4], vvB[4];

  #define LOADG(g, krd, vvd)                                                   \
    { _Pragma("unroll") for (int i = 0; i < 4; i++) {                          \
        size_t s = (size_t)(s0 + (g) * 4 + i) * (size_t)(H_ * D_);             \
        krd[i] = Kb[s]; vvd[i] = Vb[s]; } }

  #define COMPG(krd, vvd)                                                      \
    { float fk[4];                                                             \
      _Pragma("unroll") for (int i = 0; i < 4; i++) {                          \
        fk[i] = elu1(krd[i]); ksacc += fk[i]; stg[i * 64 + lane] = fk[i]; }    \
      _Pragma("unroll") for (int i = 0; i < 4; i++) {                          \
        _Pragma("unroll") for (int d4 = 0; d4 < 16; d4++) {                    \
          float4 kb = *(const float4*)&stg[i * 64 + d4 * 4];                   \
          acc[d4 * 4 + 0] = fmaf(kb.x, vvd[i], acc[d4 * 4 + 0]);               \
          acc[d4 * 4 + 1] = fmaf(kb.y, vvd[i], acc[d4 * 4 + 1]);               \
          acc[d4 * 4 + 2] = fmaf(kb.z, vvd[i], acc[d4 * 4 + 2]);               \
          acc[d4 * 4 + 3] = fmaf(kb.w, vvd[i], acc[d4 * 4 + 3]); } } }

  LOADG(0, krA, vvA);
  #pragma unroll 1
  for (int gp = 0; gp < 8; gp++) {
    LOADG(2 * gp + 1, krB, vvB);   // prefetch odd group
    COMPG(krA, vvA);               // compute even group
    if (gp < 7) { LOADG(2 * gp + 2, krA, vvA); }  // prefetch next even
    COMPG(krB, vvB);               // compute odd group
  }
  #undef LOADG
  #undef COMPG

  // block-level reduction in LDS, then one set of global atomics per block
  __syncthreads();
  #pragma unroll
  for (int j = 0; j < 16; j++) smem[j * 256 + threadIdx.x] = 0.0f;
  if (threadIdx.x < 64) ksm[threadIdx.x] = 0.0f;
  __syncthreads();
  #pragma unroll
  for (int d = 0; d < 64; d++) atomicAdd(&smem[d * 64 + lane], acc[d]);
  atomicAdd(&ksm[lane], ksacc);
  __syncthreads();
  const size_t kvoff = (size_t)(n * H_ + h) * (D_ * E_);
  #pragma unroll
  for (int j = 0; j < 16; j++) {
    int idx = j * 256 + threadIdx.x;
    atomicAdd(&kvg[kvoff + idx], smem[idx]);
  }
  if (threadIdx.x < 64)
    atomicAdd(&ksg[(n * H_ + h) * 64 + threadIdx.x], ksm[threadIdx.x]);
}

// ---------------- phase 2: out[l][e] = (fQ[l] . KV[:,e]) * rcp(fQ[l].Ksum + eps) ----------------
// grid (L/64, H, N), block 256 (4 waves). Block handles 64 l-rows; wave w owns rows [16w,16w+16).
__global__ __launch_bounds__(256) void p2_out(const float* __restrict__ queries,
                                              const float* __restrict__ kvg,
                                              const float* __restrict__ ksg,
                                              float* __restrict__ out) {
  const int lt = blockIdx.x, h = blockIdx.y, n = blockIdx.z;
  const int wave = threadIdx.x >> 6, lane = threadIdx.x & 63;
  __shared__ float q_lds[64][68];   // stride 68 dwords: 16B-aligned rows, spread banks
  __shared__ float denom_lds[64];

  // KV column e=lane into registers
  const float* kvb = kvg + (size_t)(n * H_ + h) * (D_ * E_);
  float kvreg[64];
  #pragma unroll
  for (int d = 0; d < 64; d++) kvreg[d] = kvb[d * 64 + lane];

  // Ksum slice for denominator mini-pass: lane = p*16 + rr
  const int p = lane >> 4, rr = lane & 15;
  float ksreg[16];
  const float* ksb = ksg + (n * H_ + h) * 64;
  #pragma unroll
  for (int i = 0; i < 16; i++) ksreg[i] = ksb[p * 16 + i];

  // stage fQ tile (64 rows x 64) coalesced: 16 rows per pass, float4 per thread
  const float* qb = queries + ((size_t)(n * L_ + lt * 64) * H_ + h) * D_;
  #pragma unroll
  for (int pass = 0; pass < 4; pass++) {
    int r = pass * 16 + (threadIdx.x >> 4);
    int d4 = (threadIdx.x & 15) * 4;
    float4 qv = *(const float4*)&qb[(size_t)r * (H_ * D_) + d4];
    float4 f;
    f.x = elu1(qv.x); f.y = elu1(qv.y); f.z = elu1(qv.z); f.w = elu1(qv.w);
    *(float4*)&q_lds[r][d4] = f;
  }
  __syncthreads();

  // denominator: row r = wave*16+rr, part p covers d in [16p,16p+16)
  {
    int r = wave * 16 + rr;
    float d0 = 0, d1 = 0, d2 = 0, d3 = 0;
    #pragma unroll
    for (int i = 0; i < 16; i += 4) {
      float4 qq = *(const float4*)&q_lds[r][p * 16 + i];
      d0 = fmaf(qq.x, ksreg[i + 0], d0);
      d1 = fmaf(qq.y, ksreg[i + 1], d1);
      d2 = fmaf(qq.z, ksreg[i + 2], d2);
      d3 = fmaf(qq.w, ksreg[i + 3], d3);
    }
    float dsum = (d0 + d1) + (d2 + d3);
    dsum += __shfl_xor(dsum, 16, 64);
    dsum += __shfl_xor(dsum, 32, 64);
    if (p == 0) denom_lds[r] = dsum;
  }
  __syncthreads();

  float* ob = out + ((size_t)(n * L_ + lt * 64) * H_ + h) * E_ + lane;
  #pragma unroll 2
  for (int r2 = 0; r2 < 16; r2++) {
    int r = wave * 16 + r2;
    float a0 = 0, a1 = 0, a2 = 0, a3 = 0;
    #pragma unroll
    for (int d4 = 0; d4 < 16; d4++) {
      float4 qq = *(const float4*)&q_lds[r][d4 * 4];  // uniform-address broadcast
      a0 = fmaf(qq.x, kvreg[d4 * 4 + 0], a0);
      a1 = fmaf(qq.y, kvreg[d4 * 4 + 1], a1);
      a2 = fmaf(qq.z, kvreg[d4 * 4 + 2], a2);
      a3 = fmaf(qq.w, kvreg[d4 * 4 + 3], a3);
    }
    float num = (a0 + a1) + (a2 + a3);
#if __has_builtin(__builtin_amdgcn_rcpf)
    float z = __builtin_amdgcn_rcpf(denom_lds[r] + EPS_);
#else
    float z = 1.0f / (denom_lds[r] + EPS_);
#endif
    ob[(size_t)r * (H_ * E_)] = num * z;
  }
}

extern "C" void kernel_launch(void* const* d_in, const int* in_sizes, int n_in,
                              void* d_out, int out_size, void* d_ws, size_t ws_size,
                              hipStream_t stream) {
  const float* q = (const float*)d_in[0];
  const float* k = (const float*)d_in[1];
  const float* v = (const float*)d_in[2];
  float* outp = (float*)d_out;
  float* kvg = (float*)d_ws;                                  // N*H*D*E floats
  float* ksg = kvg + (size_t)N_ * H_ * D_ * E_;               // N*H*D floats

  const int ztot = N_ * H_ * (D_ * E_ + D_);                  // 133120 floats
  const int zn4 = ztot / 4;                                   // 33280 float4s
  hipLaunchKernelGGL(zero_ws_kernel, dim3((zn4 + 255) / 256), dim3(256), 0, stream,
                     (float4*)kvg, zn4);
  hipLaunchKernelGGL(p1_kv, dim3(32, H_, N_), dim3(256), 0, stream, k, v, kvg, ksg);
  hipLaunchKernelGGL(p2_out, dim3(L_ / 64, H_, N_), dim3(256), 0, stream, q, kvg, ksg, outp);
}

// Round 2
// 138.397 us; speedup vs baseline: 1.6526x; 1.6526x over previous
//
#include <hip/hip_runtime.h>
#include <cstdint>

#define N_ 4
#define L_ 8192
#define S_ 8192
#define H_ 8
#define D_ 64
#define E_ 64
#define EPS_ 1e-6f
#define RS_ 68   // LDS row stride (floats): 16B-aligned, bank-balanced

__device__ __forceinline__ float elu1(float x) {
  return x > 0.0f ? x + 1.0f : __expf(x);
}

// ---------------- zero init for KV/Ksum accumulators ----------------
__global__ void zero_ws_kernel(float4* p, int n4) {
  int i = blockIdx.x * blockDim.x + threadIdx.x;
  if (i < n4) p[i] = make_float4(0.f, 0.f, 0.f, 0.f);
}

// ---------------- phase 1: KV[d][e] = sum_s fK[s][d] * V[s][e]; Ksum[d] -----
// grid (32, H, N), block 256 (4 waves). Block covers 256 s-rows (4 tiles of 64).
// Wave w owns d-slice [16w,16w+16). Lane (sg=lane>>4, eg=lane&15): s-split 4-way,
// 4 e-columns per lane. acc[16][4] per lane; shfl butterfly collapses sg at end.
__global__ __launch_bounds__(256, 4) void p1_kv(const float* __restrict__ keys,
                                                const float* __restrict__ values,
                                                float* __restrict__ kvg,
                                                float* __restrict__ ksg) {
  const int chunk = blockIdx.x, h = blockIdx.y, n = blockIdx.z;
  const int tid = threadIdx.x;
  const int wave = tid >> 6, lane = tid & 63;
  const int sg = lane >> 4;        // s-subgroup 0..3
  const int eg = lane & 15;        // e-group (owns e = 4*eg .. 4*eg+3)
  __shared__ float fk_lds[64 * RS_];
  __shared__ float v_lds[64 * RS_];

  const int srow = tid >> 4;            // staging row-within-pass 0..15
  const int scol = (tid & 15) * 4;      // staging col (float4)

  const float* Kb = keys   + (size_t)n * S_ * (H_ * D_) + h * D_;
  const float* Vb = values + (size_t)n * S_ * (H_ * D_) + h * D_;

  float acc[16][4];
  #pragma unroll
  for (int i = 0; i < 16; ++i)
    #pragma unroll
    for (int j = 0; j < 4; ++j) acc[i][j] = 0.0f;
  float4 kss = make_float4(0.f, 0.f, 0.f, 0.f);

  const int dbase = wave * 16;

  #pragma unroll 1
  for (int t = 0; t < 4; ++t) {
    const int s0 = chunk * 256 + t * 64;
    // ---- stage 64 rows: K (with elu) and V, coalesced float4 ----
    #pragma unroll
    for (int p = 0; p < 4; ++p) {
      const int r = p * 16 + srow;
      const size_t g = (size_t)(s0 + r) * (H_ * D_) + scol;
      float4 k4 = *(const float4*)(Kb + g);
      float4 v4 = *(const float4*)(Vb + g);
      float4 f;
      f.x = elu1(k4.x); f.y = elu1(k4.y); f.z = elu1(k4.z); f.w = elu1(k4.w);
      kss.x += f.x; kss.y += f.y; kss.z += f.z; kss.w += f.w;
      *(float4*)&fk_lds[r * RS_ + scol] = f;
      *(float4*)&v_lds[r * RS_ + scol]  = v4;
    }
    __syncthreads();
    // ---- compute: 16 s-groups of 4 rows; lane handles row 4g+sg ----
    #pragma unroll 4
    for (int g4 = 0; g4 < 16; ++g4) {
      const int s = g4 * 4 + sg;
      const float* fr = &fk_lds[s * RS_ + dbase];
      float4 vv = *(const float4*)&v_lds[s * RS_ + eg * 4];
      float4 k0 = *(const float4*)(fr + 0);
      float4 k1 = *(const float4*)(fr + 4);
      float4 k2 = *(const float4*)(fr + 8);
      float4 k3 = *(const float4*)(fr + 12);
      #define ACCROW(di, kc)                          \
        acc[di][0] = fmaf(kc, vv.x, acc[di][0]);      \
        acc[di][1] = fmaf(kc, vv.y, acc[di][1]);      \
        acc[di][2] = fmaf(kc, vv.z, acc[di][2]);      \
        acc[di][3] = fmaf(kc, vv.w, acc[di][3]);
      ACCROW(0,  k0.x) ACCROW(1,  k0.y) ACCROW(2,  k0.z) ACCROW(3,  k0.w)
      ACCROW(4,  k1.x) ACCROW(5,  k1.y) ACCROW(6,  k1.z) ACCROW(7,  k1.w)
      ACCROW(8,  k2.x) ACCROW(9,  k2.y) ACCROW(10, k2.z) ACCROW(11, k2.w)
      ACCROW(12, k3.x) ACCROW(13, k3.y) ACCROW(14, k3.z) ACCROW(15, k3.w)
      #undef ACCROW
    }
    __syncthreads();
  }

  // ---- butterfly-reduce the 4-way s split ----
  #pragma unroll
  for (int i = 0; i < 16; ++i)
    #pragma unroll
    for (int j = 0; j < 4; ++j) {
      float v = acc[i][j];
      v += __shfl_xor(v, 16, 64);
      v += __shfl_xor(v, 32, 64);
      acc[i][j] = v;
    }

  // ---- global atomics: lanes 0..15 (sg==0) commit the wave's 16x64 slice ----
  const size_t kvoff = (size_t)(n * H_ + h) * (D_ * E_);
  if (lane < 16) {
    #pragma unroll
    for (int i = 0; i < 16; ++i)
      #pragma unroll
      for (int j = 0; j < 4; ++j)
        atomicAdd(&kvg[kvoff + (size_t)(dbase + i) * E_ + lane * 4 + j], acc[i][j]);
  }

  // ---- Ksum block-reduce (reuse fk_lds; compute reads all done) ----
  *(float4*)&fk_lds[srow * 64 + scol] = kss;
  __syncthreads();
  if (tid < 64) {
    float s = 0.f;
    #pragma unroll
    for (int r = 0; r < 16; ++r) s += fk_lds[r * 64 + tid];
    atomicAdd(&ksg[(size_t)(n * H_ + h) * D_ + tid], s);
  }
}

// ---------------- phase 2: out[l][e] = (fQ[l].KV[:,e]) / (fQ[l].Ksum + eps) ---
// grid (L/64, H, N), block 256 (4 waves), wave handles 16 rows.
// Lane (dg=lane>>4, eg=lane&15): d-reduction split 4-way, 4 e-columns per lane.
__global__ __launch_bounds__(256, 4) void p2_out(const float* __restrict__ queries,
                                                 const float* __restrict__ kvg,
                                                 const float* __restrict__ ksg,
                                                 float* __restrict__ out) {
  const int lt = blockIdx.x, h = blockIdx.y, n = blockIdx.z;
  const int tid = threadIdx.x;
  const int wave = tid >> 6, lane = tid & 63;
  const int dg = lane >> 4, eg = lane & 15;
  __shared__ float q_lds[64 * RS_];
  __shared__ float den_lds[64];

  // KV sub-block into registers: kv[di][ej] = KV[16dg+di][4eg+ej]
  const float* kvb = kvg + (size_t)(n * H_ + h) * (D_ * E_);
  float kv[16][4];
  #pragma unroll
  for (int i = 0; i < 16; ++i) {
    float4 t4 = *(const float4*)&kvb[(size_t)(dg * 16 + i) * E_ + eg * 4];
    kv[i][0] = t4.x; kv[i][1] = t4.y; kv[i][2] = t4.z; kv[i][3] = t4.w;
  }
  float ks[16];
  const float* ksb = ksg + (size_t)(n * H_ + h) * D_ + dg * 16;
  #pragma unroll
  for (int i = 0; i < 16; ++i) ks[i] = ksb[i];

  // stage fQ tile [64][64] (elu applied), coalesced float4
  const float* qb = queries + ((size_t)(n * L_ + lt * 64) * H_ + h) * D_;
  {
    const int srow = tid >> 4, scol = (tid & 15) * 4;
    #pragma unroll
    for (int p = 0; p < 4; ++p) {
      const int r = p * 16 + srow;
      float4 q4 = *(const float4*)(qb + (size_t)r * (H_ * D_) + scol);
      float4 f;
      f.x = elu1(q4.x); f.y = elu1(q4.y); f.z = elu1(q4.z); f.w = elu1(q4.w);
      *(float4*)&q_lds[r * RS_ + scol] = f;
    }
  }
  __syncthreads();

  // denominator mini-pass: lane (dg,eg) -> row wave*16+eg, d-slice dg
  {
    const int r = wave * 16 + eg;
    const float* qr = &q_lds[r * RS_ + dg * 16];
    float4 a = *(const float4*)(qr + 0);
    float4 b = *(const float4*)(qr + 4);
    float4 c = *(const float4*)(qr + 8);
    float4 d = *(const float4*)(qr + 12);
    float s0 = fmaf(a.x, ks[0],  fmaf(a.y, ks[1],  fmaf(a.z, ks[2],  a.w * ks[3])));
    float s1 = fmaf(b.x, ks[4],  fmaf(b.y, ks[5],  fmaf(b.z, ks[6],  b.w * ks[7])));
    float s2 = fmaf(c.x, ks[8],  fmaf(c.y, ks[9],  fmaf(c.z, ks[10], c.w * ks[11])));
    float s3 = fmaf(d.x, ks[12], fmaf(d.y, ks[13], fmaf(d.z, ks[14], d.w * ks[15])));
    float s = (s0 + s1) + (s2 + s3);
    s += __shfl_xor(s, 16, 64);
    s += __shfl_xor(s, 32, 64);
    if (dg == 0) den_lds[r] = s;
  }
  __syncthreads();

  // main loop: 16 rows per wave; 4 broadcast b128 reads feed 64 FMAs per row
  float* ob = out + ((size_t)(n * L_ + lt * 64) * H_ + h) * E_;
  #pragma unroll 2
  for (int rr = 0; rr < 16; ++rr) {
    const int r = wave * 16 + rr;
    const float* qr = &q_lds[r * RS_ + dg * 16];
    float4 q0 = *(const float4*)(qr + 0);
    float4 q1 = *(const float4*)(qr + 4);
    float4 q2 = *(const float4*)(qr + 8);
    float4 q3 = *(const float4*)(qr + 12);
    float a0 = 0.f, a1 = 0.f, a2 = 0.f, a3 = 0.f;
    #define P2ACC(qc, i)                      \
      a0 = fmaf(qc, kv[i][0], a0);            \
      a1 = fmaf(qc, kv[i][1], a1);            \
      a2 = fmaf(qc, kv[i][2], a2);            \
      a3 = fmaf(qc, kv[i][3], a3);
    P2ACC(q0.x, 0)  P2ACC(q0.y, 1)  P2ACC(q0.z, 2)  P2ACC(q0.w, 3)
    P2ACC(q1.x, 4)  P2ACC(q1.y, 5)  P2ACC(q1.z, 6)  P2ACC(q1.w, 7)
    P2ACC(q2.x, 8)  P2ACC(q2.y, 9)  P2ACC(q2.z, 10) P2ACC(q2.w, 11)
    P2ACC(q3.x, 12) P2ACC(q3.y, 13) P2ACC(q3.z, 14) P2ACC(q3.w, 15)
    #undef P2ACC
    a0 += __shfl_xor(a0, 16, 64); a0 += __shfl_xor(a0, 32, 64);
    a1 += __shfl_xor(a1, 16, 64); a1 += __shfl_xor(a1, 32, 64);
    a2 += __shfl_xor(a2, 16, 64); a2 += __shfl_xor(a2, 32, 64);
    a3 += __shfl_xor(a3, 16, 64); a3 += __shfl_xor(a3, 32, 64);
#if __has_builtin(__builtin_amdgcn_rcpf)
    float z = __builtin_amdgcn_rcpf(den_lds[r] + EPS_);
#else
    float z = 1.0f / (den_lds[r] + EPS_);
#endif
    if (dg == 0) {
      float4 o;
      o.x = a0 * z; o.y = a1 * z; o.z = a2 * z; o.w = a3 * z;
      *(float4*)(ob + (size_t)r * (H_ * E_) + eg * 4) = o;
    }
  }
}

extern "C" void kernel_launch(void* const* d_in, const int* in_sizes, int n_in,
                              void* d_out, int out_size, void* d_ws, size_t ws_size,
                              hipStream_t stream) {
  const float* q = (const float*)d_in[0];
  const float* k = (const float*)d_in[1];
  const float* v = (const float*)d_in[2];
  float* outp = (float*)d_out;
  float* kvg = (float*)d_ws;                         // N*H*D*E floats
  float* ksg = kvg + (size_t)N_ * H_ * D_ * E_;      // N*H*D floats

  const int ztot = N_ * H_ * (D_ * E_ + D_);
  const int zn4 = ztot / 4;
  hipLaunchKernelGGL(zero_ws_kernel, dim3((zn4 + 255) / 256), dim3(256), 0, stream,
                     (float4*)kvg, zn4);
  hipLaunchKernelGGL(p1_kv, dim3(32, H_, N_), dim3(256), 0, stream, k, v, kvg, ksg);
  hipLaunchKernelGGL(p2_out, dim3(L_ / 64, H_, N_), dim3(256), 0, stream, q, kvg, ksg, outp);
}